// Round 3
// baseline (194.167 us; speedup 1.0000x reference)
//
#include <hip/hip_runtime.h>
#include <hip/hip_bf16.h>

// Problem constants: L=512, B=2, D=256, C=128, O=64
#define LL 512
#define BB 2
#define DD 256
#define CC 128
#define OO 64

typedef __attribute__((ext_vector_type(8))) short bf16x8;  // 8 bf16 (4 VGPRs)
typedef __attribute__((ext_vector_type(4))) float f32x4;   // 4 fp32 acc

__device__ __forceinline__ short f2bf(float v) {
    __hip_bfloat16 h = __float2bfloat16(v);
    return *reinterpret_cast<short*>(&h);
}
__device__ __forceinline__ float bf2f(short s) {
    __hip_bfloat16 h;
    *reinterpret_cast<short*>(&h) = s;
    return __bfloat162float(h);
}

__device__ __forceinline__ float wave_reduce_sum(float v) {
#pragma unroll
    for (int off = 32; off > 0; off >>= 1)
        v += __shfl_down(v, off, 64);
    return v;
}

// Blocks 0..1023: per (b,l) LayerNorm + projections.
// Blocks 1024..1055: pre-swizzle w3 into bf16 MFMA-fragment order:
//   w3s[ot][ks][q][ln][j] = bf16(w3[c= ks*32+q*8+j][o= ot*16+ln])
__global__ __launch_bounds__(256) void prep_kernel(
    const float* __restrict__ x,
    const float* __restrict__ gamma,
    const float* __restrict__ beta,
    const float* __restrict__ w1, const float* __restrict__ b1,
    const float* __restrict__ w2, const float* __restrict__ b2,
    const float* __restrict__ w4, const float* __restrict__ b3,
    const float* __restrict__ w3,
    float* __restrict__ a_ws, short* __restrict__ bact,
    float* __restrict__ a4b3_ws, float* __restrict__ b4_ws,
    short* __restrict__ w3s)
{
    const int blk = blockIdx.x;
    const int t = threadIdx.x;

    if (blk >= BB * LL) {
        // w3 fragment-order swizzle: e = ot*2048 + ks*512 + q*128 + ln*8 + j
        const int e  = (blk - BB * LL) * 256 + t;
        const int j  = e & 7;
        const int ln = (e >> 3) & 15;
        const int q  = (e >> 7) & 3;
        const int ks = (e >> 9) & 3;
        const int ot = e >> 11;
        const int c = ks * 32 + q * 8 + j;
        const int o = ot * 16 + ln;
        w3s[e] = f2bf(w3[c * OO + o]);
        return;
    }

    const int b = blk >> 9;
    const int l = blk & (LL - 1);

    __shared__ float ylds[DD];
    __shared__ float ab[2 * CC];
    __shared__ float red[8];

    // LayerNorm of x[l,b,:]  (x is (L,B,D))
    float xv = x[(l * BB + b) * DD + t];
    float s = wave_reduce_sum(xv);
    if ((t & 63) == 0) red[t >> 6] = s;
    __syncthreads();
    float mu = (red[0] + red[1] + red[2] + red[3]) * (1.0f / DD);
    float xc = xv - mu;
    float s2 = wave_reduce_sum(xc * xc);
    if ((t & 63) == 0) red[4 + (t >> 6)] = s2;
    __syncthreads();
    float var = (red[4] + red[5] + red[6] + red[7]) * (1.0f / DD);
    float y = xc * rsqrtf(var + 1e-5f) * gamma[t] + beta[t];
    ylds[t] = y;
    __syncthreads();

    // a (threads 0..127) / b (threads 128..255) projections:
    // float4 LDS reads + 4 independent FMA chains
    {
        const int c = t & (CC - 1);
        const float* w = (t < CC) ? w1 : w2;
        const float4* y4 = (const float4*)ylds;
        float acc0 = (t < CC) ? b1[c] : b2[c];
        float acc1 = 0.f, acc2 = 0.f, acc3 = 0.f;
#pragma unroll
        for (int i = 0; i < 64; i += 4) {
            float4 ya = y4[i], yb = y4[i + 1], yc = y4[i + 2], yd = y4[i + 3];
            const float* wp = w + i * 4 * CC + c;
            acc0 = fmaf(ya.x, wp[0 * CC], acc0);
            acc0 = fmaf(ya.y, wp[1 * CC], acc0);
            acc0 = fmaf(ya.z, wp[2 * CC], acc0);
            acc0 = fmaf(ya.w, wp[3 * CC], acc0);
            acc1 = fmaf(yb.x, wp[4 * CC], acc1);
            acc1 = fmaf(yb.y, wp[5 * CC], acc1);
            acc1 = fmaf(yb.z, wp[6 * CC], acc1);
            acc1 = fmaf(yb.w, wp[7 * CC], acc1);
            acc2 = fmaf(yc.x, wp[8 * CC], acc2);
            acc2 = fmaf(yc.y, wp[9 * CC], acc2);
            acc2 = fmaf(yc.z, wp[10 * CC], acc2);
            acc2 = fmaf(yc.w, wp[11 * CC], acc2);
            acc3 = fmaf(yd.x, wp[12 * CC], acc3);
            acc3 = fmaf(yd.y, wp[13 * CC], acc3);
            acc3 = fmaf(yd.z, wp[14 * CC], acc3);
            acc3 = fmaf(yd.w, wp[15 * CC], acc3);
        }
        float accv = (acc0 + acc1) + (acc2 + acc3);
        ab[t] = accv;
        if (t < CC) a_ws[(b * LL + l) * CC + c] = accv;
        else        bact[(b * LL + l) * CC + c] = f2bf(accv);
    }
    __syncthreads();

    // a4+b3 (threads 0..63) and b4 (threads 64..127)
    if (t < 2 * OO) {
        const int o = t & (OO - 1);
        const float4* s4 = (const float4*)((t < OO) ? ab : (ab + CC));
        float acc0 = (t < OO) ? b3[o] : 0.0f;
        float acc1 = 0.f, acc2 = 0.f, acc3 = 0.f;
#pragma unroll
        for (int i = 0; i < 32; i += 4) {
            float4 sa = s4[i], sb = s4[i + 1], sc = s4[i + 2], sd = s4[i + 3];
            const float* wp = w4 + i * 4 * OO + o;
            acc0 = fmaf(sa.x, wp[0 * OO], acc0);
            acc0 = fmaf(sa.y, wp[1 * OO], acc0);
            acc0 = fmaf(sa.z, wp[2 * OO], acc0);
            acc0 = fmaf(sa.w, wp[3 * OO], acc0);
            acc1 = fmaf(sb.x, wp[4 * OO], acc1);
            acc1 = fmaf(sb.y, wp[5 * OO], acc1);
            acc1 = fmaf(sb.z, wp[6 * OO], acc1);
            acc1 = fmaf(sb.w, wp[7 * OO], acc1);
            acc2 = fmaf(sc.x, wp[8 * OO], acc2);
            acc2 = fmaf(sc.y, wp[9 * OO], acc2);
            acc2 = fmaf(sc.z, wp[10 * OO], acc2);
            acc2 = fmaf(sc.w, wp[11 * OO], acc2);
            acc3 = fmaf(sd.x, wp[12 * OO], acc3);
            acc3 = fmaf(sd.y, wp[13 * OO], acc3);
            acc3 = fmaf(sd.z, wp[14 * OO], acc3);
            acc3 = fmaf(sd.w, wp[15 * OO], acc3);
        }
        float accv = (acc0 + acc1) + (acc2 + acc3);
        ((t < OO) ? a4b3_ws : b4_ws)[(b * LL + l) * OO + o] = accv;
    }
}

// One block per (b, l, m-half); 4 waves x 64 m. No LDS, no barriers.
// MFMA roles: A = (a[c]*w3[c,o]) built in registers from w3s frags,
//             B = Bact rows  ->  D[row=o][col=m]: lane ln owns fixed m,
//             regs r hold 4 consecutive o  -> float4 epilogue.
__global__ __launch_bounds__(256, 3) void main_kernel(
    const float* __restrict__ a_ws, const short* __restrict__ bact,
    const float* __restrict__ a4b3_ws, const float* __restrict__ b4_ws,
    const short* __restrict__ w3s,
    float* __restrict__ out)
{
    const int bid = blockIdx.x;           // b*1024 + l*2 + mh
    const int mh = bid & 1;
    const int l  = (bid >> 1) & (LL - 1);
    const int b  = bid >> 10;
    const int t  = threadIdx.x;
    const int wave = t >> 6;
    const int lane = t & 63;
    const int ln = lane & 15;
    const int q  = lane >> 4;
    const int mbase = mh * 256 + wave * 64;

    const float* arow = a_ws + (b * LL + l) * CC;
    const short* abase = bact + (size_t)(b * LL + mbase + ln) * CC + q * 8;

    f32x4 acc[4][4];                      // [ot][mt]
#pragma unroll
    for (int ot = 0; ot < 4; ++ot)
#pragma unroll
        for (int mt = 0; mt < 4; ++mt)
            acc[ot][mt] = (f32x4){0.f, 0.f, 0.f, 0.f};

#pragma unroll
    for (int ks = 0; ks < 4; ++ks) {
        const float* ap = arow + ks * 32 + q * 8;
        float av[8];
        *(float4*)&av[0] = *(const float4*)ap;
        *(float4*)&av[4] = *(const float4*)(ap + 4);

        bf16x8 wp[4];
#pragma unroll
        for (int ot = 0; ot < 4; ++ot) {
            bf16x8 wr = *(const bf16x8*)(w3s + (((ot * 4 + ks) * 4 + q) << 7) + ln * 8);
            bf16x8 r;
#pragma unroll
            for (int j = 0; j < 8; ++j)
                r[j] = f2bf(bf2f(wr[j]) * av[j]);
            wp[ot] = r;
        }

        bf16x8 bfr[4];
#pragma unroll
        for (int mt = 0; mt < 4; ++mt)
            bfr[mt] = *(const bf16x8*)(abase + mt * 16 * CC + ks * 32);

#pragma unroll
        for (int ot = 0; ot < 4; ++ot)
#pragma unroll
            for (int mt = 0; mt < 4; ++mt)
                acc[ot][mt] = __builtin_amdgcn_mfma_f32_16x16x32_bf16(
                    wp[ot], bfr[mt], acc[ot][mt], 0, 0, 0);
    }

    // Epilogue: out[b,l,m,o] = acc + a4b3[b,l,o] - b4[b,m,o]; all float4.
    const float* a4p = a4b3_ws + (b * LL + l) * OO;
    float4 a4v[4];
#pragma unroll
    for (int ot = 0; ot < 4; ++ot)
        a4v[ot] = *(const float4*)(a4p + ot * 16 + q * 4);

#pragma unroll
    for (int mt = 0; mt < 4; ++mt) {
        const int m = mbase + mt * 16 + ln;
        const float* b4p = b4_ws + (size_t)(b * LL + m) * OO;
        float* op = out + ((size_t)(b * LL + l) * LL + m) * OO;
#pragma unroll
        for (int ot = 0; ot < 4; ++ot) {
            float4 bq = *(const float4*)(b4p + ot * 16 + q * 4);
            f32x4 a = acc[ot][mt];
            float4 r;
            r.x = a[0] + a4v[ot].x - bq.x;
            r.y = a[1] + a4v[ot].y - bq.y;
            r.z = a[2] + a4v[ot].z - bq.z;
            r.w = a[3] + a4v[ot].w - bq.w;
            *(float4*)(op + ot * 16 + q * 4) = r;
        }
    }
}

extern "C" void kernel_launch(void* const* d_in, const int* in_sizes, int n_in,
                              void* d_out, int out_size, void* d_ws, size_t ws_size,
                              hipStream_t stream) {
    const float* x     = (const float*)d_in[0];
    const float* gamma = (const float*)d_in[1];
    const float* beta  = (const float*)d_in[2];
    const float* w1    = (const float*)d_in[3];
    const float* b1    = (const float*)d_in[4];
    const float* w2    = (const float*)d_in[5];
    const float* b2    = (const float*)d_in[6];
    const float* w3    = (const float*)d_in[7];
    const float* b3    = (const float*)d_in[8];
    const float* w4    = (const float*)d_in[9];
    float* out = (float*)d_out;

    char* ws = (char*)d_ws;
    float* a_ws    = (float*)ws;                       // B*L*C fp32 = 512 KB
    short* bact    = (short*)(ws + 512 * 1024);        // B*L*C bf16 = 256 KB
    float* a4b3_ws = (float*)(ws + 768 * 1024);        // B*L*O fp32 = 256 KB
    float* b4_ws   = (float*)(ws + 1024 * 1024);       // B*L*O fp32 = 256 KB
    short* w3s     = (short*)(ws + 1280 * 1024);       // 8192 bf16  = 16 KB

    prep_kernel<<<BB * LL + 32, 256, 0, stream>>>(x, gamma, beta, w1, b1, w2, b2,
                                                  w4, b3, w3,
                                                  a_ws, bact, a4b3_ws, b4_ws, w3s);
    main_kernel<<<BB * LL * 2, 256, 0, stream>>>(a_ws, bact, a4b3_ws, b4_ws,
                                                 w3s, out);
}